// Round 1
// baseline (30683.124 us; speedup 1.0000x reference)
//
#include <hip/hip_runtime.h>
#include <math.h>

#define T_ 512
#define J_ 24
#define B_ 8
#define C_ 128
#define N_ (B_*J_)        // 192
#define R_ (N_*T_)        // 98304
#define BN_EPS 1e-5f

// x layout: (B, T, J, C). Row r = n*T + t with n = b*J + j.
__device__ __forceinline__ int xbase_n(int n) {
    int b = n / J_;
    int j = n - b * J_;
    return (b * T_ * J_ + j) * C_;     // add t*(J_*C_) + c
}

// keep v[0] >= v[1] >= v[2] >= v[3]
__device__ __forceinline__ void ins4(float (&v)[4], int (&ix)[4], float nv, int ni) {
    if (nv > v[3]) {
        if (nv > v[1]) {
            if (nv > v[0]) {
                v[3]=v[2]; ix[3]=ix[2]; v[2]=v[1]; ix[2]=ix[1];
                v[1]=v[0]; ix[1]=ix[0]; v[0]=nv; ix[0]=ni;
            } else {
                v[3]=v[2]; ix[3]=ix[2]; v[2]=v[1]; ix[2]=ix[1];
                v[1]=nv; ix[1]=ni;
            }
        } else {
            if (nv > v[2]) { v[3]=v[2]; ix[3]=ix[2]; v[2]=nv; ix[2]=ni; }
            else           { v[3]=nv; ix[3]=ni; }
        }
    }
}

// ---------------- Kernel 1: sim = X_n X_n^T rowwise top-4 neighbor indices ----
// block: 256 threads, one n, 32 t-rows. s processed in 2 halves of 256.
// A_l: [k(128)][t(32)]  B_l: [k(32)][s(256)]
__global__ __launch_bounds__(256) void k_sim_topk(const float* __restrict__ x,
                                                  int* __restrict__ nbr) {
    __shared__ float A_l[128 * 32];
    __shared__ float B_l[32 * 256];
    const int bx  = blockIdx.x;
    const int n   = bx >> 4;
    const int t0  = (bx & 15) << 5;
    const int tid = threadIdx.x;
    const int xb  = xbase_n(n);

    // stage A (32 rows x 128 k), transposed to [k][t]
    #pragma unroll
    for (int p = 0; p < 4; ++p) {
        int f4  = tid + (p << 8);          // 0..1023
        int row = f4 >> 5;                 // 32 f4 per row
        int kq  = f4 & 31;
        float4 v = *(const float4*)(x + xb + (t0 + row) * (J_*C_) + (kq << 2));
        A_l[(kq*4+0)*32 + row] = v.x;
        A_l[(kq*4+1)*32 + row] = v.y;
        A_l[(kq*4+2)*32 + row] = v.z;
        A_l[(kq*4+3)*32 + row] = v.w;
    }

    const int tg = tid >> 5;   // 0..7 -> rows tg*4..+3
    const int sg = tid & 31;   // cols sg*8..+7

    float tv[4][4]; int ti[4][4];
    #pragma unroll
    for (int i = 0; i < 4; ++i)
        #pragma unroll
        for (int q = 0; q < 4; ++q) { tv[i][q] = -INFINITY; ti[i][q] = 0; }

    for (int half = 0; half < 2; ++half) {
        const int s0 = half << 8;
        float acc[4][8];
        #pragma unroll
        for (int i = 0; i < 4; ++i)
            #pragma unroll
            for (int j = 0; j < 8; ++j) acc[i][j] = 0.f;

        for (int kc = 0; kc < 4; ++kc) {
            __syncthreads();
            // stage B: 256 s-rows x 32 k, transposed to [k][s]
            #pragma unroll
            for (int p = 0; p < 8; ++p) {
                int f4   = tid + (p << 8);     // 0..2047
                int srow = f4 >> 3;            // 8 f4 per row
                int kq   = f4 & 7;
                float4 v = *(const float4*)(x + xb + (s0 + srow) * (J_*C_)
                                            + (kc << 5) + (kq << 2));
                B_l[(kq*4+0)*256 + srow] = v.x;
                B_l[(kq*4+1)*256 + srow] = v.y;
                B_l[(kq*4+2)*256 + srow] = v.z;
                B_l[(kq*4+3)*256 + srow] = v.w;
            }
            __syncthreads();
            const int kb = kc << 5;
            for (int kk = 0; kk < 32; ++kk) {
                float4 a0 = *(const float4*)&A_l[(kb + kk)*32 + tg*4];
                float4 b0 = *(const float4*)&B_l[kk*256 + sg*8];
                float4 b1 = *(const float4*)&B_l[kk*256 + sg*8 + 4];
                float av[4] = {a0.x, a0.y, a0.z, a0.w};
                float bv[8] = {b0.x, b0.y, b0.z, b0.w, b1.x, b1.y, b1.z, b1.w};
                #pragma unroll
                for (int i = 0; i < 4; ++i)
                    #pragma unroll
                    for (int j = 0; j < 8; ++j)
                        acc[i][j] = fmaf(av[i], bv[j], acc[i][j]);
            }
        }
        // fold this half's sims into per-thread running top-4
        #pragma unroll
        for (int i = 0; i < 4; ++i)
            #pragma unroll
            for (int j = 0; j < 8; ++j)
                ins4(tv[i], ti[i], acc[i][j], s0 + sg*8 + j);
    }

    // merge the 32 s-groups per row via LDS (overlay on B_l: 16KB vals + 16KB idx)
    __syncthreads();
    float* scv = B_l;
    int*   sci = (int*)(B_l + 4096);
    #pragma unroll
    for (int i = 0; i < 4; ++i) {
        int tl = tg*4 + i;
        #pragma unroll
        for (int q = 0; q < 4; ++q) {
            scv[(tl*32 + sg)*4 + q] = tv[i][q];
            sci[(tl*32 + sg)*4 + q] = ti[i][q];
        }
    }
    __syncthreads();
    if (tid < 32) {
        float mv[4]; int mi[4];
        #pragma unroll
        for (int q = 0; q < 4; ++q) { mv[q] = -INFINITY; mi[q] = 0; }
        for (int g = 0; g < 32; ++g)
            #pragma unroll
            for (int q = 0; q < 4; ++q)
                ins4(mv, mi, scv[(tid*32 + g)*4 + q], sci[(tid*32 + g)*4 + q]);
        int r = n*T_ + t0 + tid;
        *(int4*)(nbr + (size_t)r*4) = make_int4(mi[0], mi[1], mi[2], mi[3]);
    }
}

// ---------------- Kernel 2: vx = xr Vw^T + Vb ; ux = xr Uw^T + Ub -------------
// block: 256 threads, 128 rows x 64 out-cols. k chunks of 32.
__global__ __launch_bounds__(256) void k_vxux(const float* __restrict__ x,
        const float* __restrict__ Vw, const float* __restrict__ Vb,
        const float* __restrict__ Uw, const float* __restrict__ Ub,
        float* __restrict__ vx, float* __restrict__ ux) {
    __shared__ float A_l[32 * 128];   // [k][row]
    __shared__ float W_l[32 * 64];    // [k][d]
    const int bx  = blockIdx.x;
    const int rt  = bx >> 2;
    const int ct  = bx & 3;
    const int tid = threadIdx.x;
    const int rg  = tid >> 4;         // 0..15 -> rows rg*8..+7
    const int cg  = tid & 15;         // cols cg*4..+3
    const int r0  = rt << 7;
    const int n   = r0 >> 9;
    const int xb  = xbase_n(n);
    const int tb  = r0 & 511;
    const bool isV = (ct < 2);
    const float* Wsrc = isV ? Vw : Uw;
    const int d0 = (ct & 1) << 6;

    float acc[8][4];
    #pragma unroll
    for (int i = 0; i < 8; ++i)
        #pragma unroll
        for (int j = 0; j < 4; ++j) acc[i][j] = 0.f;

    for (int kc = 0; kc < 4; ++kc) {
        __syncthreads();
        #pragma unroll
        for (int p = 0; p < 4; ++p) {                  // A: 128 rows x 32 k
            int f4  = tid + (p << 8);                  // 0..1023
            int row = f4 >> 3;
            int kq  = f4 & 7;
            float4 v = *(const float4*)(x + xb + (tb + row) * (J_*C_)
                                        + (kc << 5) + (kq << 2));
            A_l[(kq*4+0)*128 + row] = v.x;
            A_l[(kq*4+1)*128 + row] = v.y;
            A_l[(kq*4+2)*128 + row] = v.z;
            A_l[(kq*4+3)*128 + row] = v.w;
        }
        #pragma unroll
        for (int p = 0; p < 2; ++p) {                  // W: 64 d x 32 k
            int f4 = tid + (p << 8);                   // 0..511
            int dl = f4 >> 3;
            int kq = f4 & 7;
            float4 v = *(const float4*)(Wsrc + (d0 + dl) * C_ + (kc << 5) + (kq << 2));
            W_l[(kq*4+0)*64 + dl] = v.x;
            W_l[(kq*4+1)*64 + dl] = v.y;
            W_l[(kq*4+2)*64 + dl] = v.z;
            W_l[(kq*4+3)*64 + dl] = v.w;
        }
        __syncthreads();
        for (int kk = 0; kk < 32; ++kk) {
            float4 a0 = *(const float4*)&A_l[kk*128 + rg*8];
            float4 a1 = *(const float4*)&A_l[kk*128 + rg*8 + 4];
            float4 w  = *(const float4*)&W_l[kk*64 + cg*4];
            float av[8] = {a0.x,a0.y,a0.z,a0.w,a1.x,a1.y,a1.z,a1.w};
            float wv[4] = {w.x,w.y,w.z,w.w};
            #pragma unroll
            for (int i = 0; i < 8; ++i)
                #pragma unroll
                for (int j = 0; j < 4; ++j)
                    acc[i][j] = fmaf(av[i], wv[j], acc[i][j]);
        }
    }

    const float* bias = isV ? Vb : Ub;
    float4 bb = *(const float4*)(bias + d0 + cg*4);
    float* dst = isV ? vx : ux;
    #pragma unroll
    for (int i = 0; i < 8; ++i) {
        int r = r0 + rg*8 + i;
        float4 o;
        o.x = acc[i][0] + bb.x; o.y = acc[i][1] + bb.y;
        o.z = acc[i][2] + bb.z; o.w = acc[i][3] + bb.w;
        *(float4*)(dst + (size_t)r*C_ + d0 + cg*4) = o;
    }
}

// ---------------- Kernel 3: out_pre = 0.25*sum(vx[nbr]) + ux ; BN partial sums -
__global__ __launch_bounds__(256) void k_agg(const float* __restrict__ vx,
        float* __restrict__ ux, const int* __restrict__ nbr,
        float* __restrict__ stats) {
    __shared__ float red[256 * 8];
    const int tid = threadIdx.x;
    const int r0  = blockIdx.x << 6;
    const int cq  = tid & 31;
    const int rl  = tid >> 5;
    float s0=0,s1=0,s2=0,s3=0, q0=0,q1=0,q2=0,q3=0;
    const float4* vr = (const float4*)vx;
    for (int p = 0; p < 8; ++p) {
        int r = r0 + (p << 3) + rl;
        int4 nb = *(const int4*)(nbr + ((size_t)r << 2));
        int base = (r >> 9) << 9;
        float4 a  = *(const float4*)(ux + (size_t)r*C_ + (cq << 2));
        float4 v0 = vr[(size_t)(base + nb.x)*32 + cq];
        float4 v1 = vr[(size_t)(base + nb.y)*32 + cq];
        float4 v2 = vr[(size_t)(base + nb.z)*32 + cq];
        float4 v3 = vr[(size_t)(base + nb.w)*32 + cq];
        a.x += 0.25f * (v0.x + v1.x + v2.x + v3.x);
        a.y += 0.25f * (v0.y + v1.y + v2.y + v3.y);
        a.z += 0.25f * (v0.z + v1.z + v2.z + v3.z);
        a.w += 0.25f * (v0.w + v1.w + v2.w + v3.w);
        *(float4*)(ux + (size_t)r*C_ + (cq << 2)) = a;
        s0 += a.x; s1 += a.y; s2 += a.z; s3 += a.w;
        q0 += a.x*a.x; q1 += a.y*a.y; q2 += a.z*a.z; q3 += a.w*a.w;
    }
    red[tid*8+0]=s0; red[tid*8+1]=s1; red[tid*8+2]=s2; red[tid*8+3]=s3;
    red[tid*8+4]=q0; red[tid*8+5]=q1; red[tid*8+6]=q2; red[tid*8+7]=q3;
    __syncthreads();
    if (tid < 32) {
        for (int g = 1; g < 8; ++g) {
            int o = (tid + 32*g)*8;
            s0 += red[o+0]; s1 += red[o+1]; s2 += red[o+2]; s3 += red[o+3];
            q0 += red[o+4]; q1 += red[o+5]; q2 += red[o+6]; q3 += red[o+7];
        }
        int c0 = tid*4;
        atomicAdd(&stats[c0+0], s0); atomicAdd(&stats[c0+1], s1);
        atomicAdd(&stats[c0+2], s2); atomicAdd(&stats[c0+3], s3);
        atomicAdd(&stats[128+c0+0], q0); atomicAdd(&stats[128+c0+1], q1);
        atomicAdd(&stats[128+c0+2], q2); atomicAdd(&stats[128+c0+3], q3);
    }
}

// ---------------- Kernel 4: BN normalize + residual + ReLU + transpose --------
__global__ __launch_bounds__(256) void k_fin(const float* __restrict__ x,
        const float* __restrict__ pre, const float* __restrict__ stats,
        const float* __restrict__ gamma, const float* __restrict__ beta,
        float* __restrict__ out) {
    const int id = blockIdx.x * 256 + threadIdx.x;   // float4 id
    const int r  = id >> 5;
    const int c0 = (id & 31) << 2;
    const float inv = 1.0f / (float)R_;
    float4 s  = *(const float4*)(stats + c0);
    float4 sq = *(const float4*)(stats + 128 + c0);
    float4 g  = *(const float4*)(gamma + c0);
    float4 bt = *(const float4*)(beta + c0);
    float m0 = s.x*inv, m1 = s.y*inv, m2 = s.z*inv, m3 = s.w*inv;
    float sc0 = g.x * rsqrtf(sq.x*inv - m0*m0 + BN_EPS);
    float sc1 = g.y * rsqrtf(sq.y*inv - m1*m1 + BN_EPS);
    float sc2 = g.z * rsqrtf(sq.z*inv - m2*m2 + BN_EPS);
    float sc3 = g.w * rsqrtf(sq.w*inv - m3*m3 + BN_EPS);
    float sh0 = bt.x - m0*sc0, sh1 = bt.y - m1*sc1;
    float sh2 = bt.z - m2*sc2, sh3 = bt.w - m3*sc3;
    int n = r >> 9, t = r & 511;
    int off = xbase_n(n) + t*(J_*C_) + c0;
    float4 xv = *(const float4*)(x + off);
    float4 p  = *(const float4*)(pre + (size_t)r*C_ + c0);
    float4 y;
    y.x = xv.x + p.x*sc0 + sh0; y.y = xv.y + p.y*sc1 + sh1;
    y.z = xv.z + p.z*sc2 + sh2; y.w = xv.w + p.w*sc3 + sh3;
    y.x = y.x > 0.f ? y.x : 0.f; y.y = y.y > 0.f ? y.y : 0.f;
    y.z = y.z > 0.f ? y.z : 0.f; y.w = y.w > 0.f ? y.w : 0.f;
    *(float4*)(out + off) = y;
}

extern "C" void kernel_launch(void* const* d_in, const int* in_sizes, int n_in,
                              void* d_out, int out_size, void* d_ws, size_t ws_size,
                              hipStream_t stream) {
    const float* x     = (const float*)d_in[0];
    const float* Uw    = (const float*)d_in[1];
    const float* Ub    = (const float*)d_in[2];
    const float* Vw    = (const float*)d_in[3];
    const float* Vb    = (const float*)d_in[4];
    const float* gamma = (const float*)d_in[5];
    const float* beta  = (const float*)d_in[6];
    float* out = (float*)d_out;

    // workspace layout: ux/out_pre (R*C f32) | nbr (R*4 i32) | stats (256 f32)
    float* ux    = (float*)d_ws;
    int*   nbr   = (int*)(ux + (size_t)R_ * C_);
    float* stats = (float*)(nbr + (size_t)R_ * 4);
    float* vx    = out;   // d_out doubles as vx scratch; overwritten by k_fin

    hipMemsetAsync(stats, 0, 256 * sizeof(float), stream);
    k_sim_topk<<<N_ * 16, 256, 0, stream>>>(x, nbr);
    k_vxux<<<(R_ / 128) * 4, 256, 0, stream>>>(x, Vw, Vb, Uw, Ub, vx, ux);
    k_agg<<<R_ / 64, 256, 0, stream>>>(vx, ux, nbr, stats);
    k_fin<<<(R_ * 32) / 256, 256, 0, stream>>>(x, ux, stats, gamma, beta, out);
}

// Round 2
// 514.980 us; speedup vs baseline: 59.5812x; 59.5812x over previous
//
#include <hip/hip_runtime.h>
#include <math.h>

#define T_ 512
#define J_ 24
#define B_ 8
#define C_ 128
#define N_ (B_*J_)        // 192
#define R_ (N_*T_)        // 98304
#define BN_EPS 1e-5f

// x layout: (B, T, J, C). Row r = n*T + t with n = b*J + j.
__device__ __forceinline__ int xbase_n(int n) {
    int b = n / J_;
    int j = n - b * J_;
    return (b * T_ * J_ + j) * C_;     // add t*(J_*C_) + c
}

// keep v[0] >= v[1] >= v[2] >= v[3]
__device__ __forceinline__ void ins4(float (&v)[4], int (&ix)[4], float nv, int ni) {
    if (nv > v[3]) {
        if (nv > v[1]) {
            if (nv > v[0]) {
                v[3]=v[2]; ix[3]=ix[2]; v[2]=v[1]; ix[2]=ix[1];
                v[1]=v[0]; ix[1]=ix[0]; v[0]=nv; ix[0]=ni;
            } else {
                v[3]=v[2]; ix[3]=ix[2]; v[2]=v[1]; ix[2]=ix[1];
                v[1]=nv; ix[1]=ni;
            }
        } else {
            if (nv > v[2]) { v[3]=v[2]; ix[3]=ix[2]; v[2]=nv; ix[2]=ni; }
            else           { v[3]=nv; ix[3]=ni; }
        }
    }
}

// ---------------- Kernel 1: sim = X_n X_n^T rowwise top-4 neighbor indices ----
// block: 256 threads, one n, 32 t-rows; s processed in 2 halves of 256.
// A_l: row-major [32][132] (padded).  B_l: [k(32)][s(256)] with XOR swizzle
// col' = col ^ (((k>>2)&3)<<3)  (bits 3-4 only -> float4 reads stay contiguous).
__global__ __launch_bounds__(256) void k_sim_topk(const float* __restrict__ x,
                                                  int* __restrict__ nbr) {
    __shared__ float A_l[32 * 132];
    __shared__ float B_l[32 * 256];
    const int bx  = blockIdx.x;
    const int n   = bx >> 4;
    const int t0  = (bx & 15) << 5;
    const int tid = threadIdx.x;
    const int xb  = xbase_n(n);

    // stage A (32 rows x 128 k), row-major padded. Conflict-free float4 stores.
    #pragma unroll
    for (int p = 0; p < 4; ++p) {
        int f4  = tid + (p << 8);          // 0..1023
        int row = f4 >> 5;                 // 32 f4 per row
        int kq  = f4 & 31;
        float4 v = *(const float4*)(x + xb + (t0 + row) * (J_*C_) + (kq << 2));
        *(float4*)&A_l[row * 132 + (kq << 2)] = v;
    }

    const int tg = tid >> 5;   // 0..7 -> rows tg*4..+3
    const int sg = tid & 31;   // cols sg*8..+7

    float tv[4][4]; int ti[4][4];
    #pragma unroll
    for (int i = 0; i < 4; ++i)
        #pragma unroll
        for (int q = 0; q < 4; ++q) { tv[i][q] = -INFINITY; ti[i][q] = 0; }

    #pragma unroll 1
    for (int half = 0; half < 2; ++half) {
        const int s0 = half << 8;
        float acc[4][8];
        #pragma unroll
        for (int i = 0; i < 4; ++i)
            #pragma unroll
            for (int j = 0; j < 8; ++j) acc[i][j] = 0.f;

        #pragma unroll 1
        for (int kc = 0; kc < 4; ++kc) {
            __syncthreads();
            // stage B: 256 s-rows x 32 k, transposed + swizzled.
            // (srow, kq): global load is 8 lanes x 16B = 128B contiguous per row.
            #pragma unroll
            for (int p = 0; p < 8; ++p) {
                int f4   = tid + (p << 8);     // 0..2047
                int srow = f4 >> 3;            // 8 f4 per row
                int kq   = f4 & 7;
                float4 v = *(const float4*)(x + xb + (s0 + srow) * (J_*C_)
                                            + (kc << 5) + (kq << 2));
                int colp = srow ^ ((kq & 3) << 3);   // swizzled column
                B_l[(kq*4+0)*256 + colp] = v.x;
                B_l[(kq*4+1)*256 + colp] = v.y;
                B_l[(kq*4+2)*256 + colp] = v.z;
                B_l[(kq*4+3)*256 + colp] = v.w;
            }
            __syncthreads();
            const int kb = kc << 5;
            #pragma unroll 4
            for (int kk = 0; kk < 32; ++kk) {
                const int X  = ((kk >> 2) & 3) << 3;
                const int cb = kk*256 + ((sg << 3) ^ X);
                float4 b0 = *(const float4*)&B_l[cb];
                float4 b1 = *(const float4*)&B_l[cb + 4];
                float a0 = A_l[(tg*4+0)*132 + kb + kk];
                float a1 = A_l[(tg*4+1)*132 + kb + kk];
                float a2 = A_l[(tg*4+2)*132 + kb + kk];
                float a3 = A_l[(tg*4+3)*132 + kb + kk];
                float bv[8] = {b0.x, b0.y, b0.z, b0.w, b1.x, b1.y, b1.z, b1.w};
                float av[4] = {a0, a1, a2, a3};
                #pragma unroll
                for (int i = 0; i < 4; ++i)
                    #pragma unroll
                    for (int j = 0; j < 8; ++j)
                        acc[i][j] = fmaf(av[i], bv[j], acc[i][j]);
            }
        }
        // fold this half's sims into per-thread running top-4
        #pragma unroll
        for (int i = 0; i < 4; ++i)
            #pragma unroll
            for (int j = 0; j < 8; ++j)
                ins4(tv[i], ti[i], acc[i][j], s0 + sg*8 + j);
    }

    // merge the 32 s-groups per row via LDS (overlay on B_l: 16KB vals + 16KB idx)
    __syncthreads();
    float* scv = B_l;
    int*   sci = (int*)(B_l + 4096);
    #pragma unroll
    for (int i = 0; i < 4; ++i) {
        int tl = tg*4 + i;
        #pragma unroll
        for (int q = 0; q < 4; ++q) {
            scv[(tl*32 + sg)*4 + q] = tv[i][q];
            sci[(tl*32 + sg)*4 + q] = ti[i][q];
        }
    }
    __syncthreads();
    if (tid < 32) {
        float mv[4]; int mi[4];
        #pragma unroll
        for (int q = 0; q < 4; ++q) { mv[q] = -INFINITY; mi[q] = 0; }
        for (int g = 0; g < 32; ++g)
            #pragma unroll
            for (int q = 0; q < 4; ++q)
                ins4(mv, mi, scv[(tid*32 + g)*4 + q], sci[(tid*32 + g)*4 + q]);
        int r = n*T_ + t0 + tid;
        *(int4*)(nbr + (size_t)r*4) = make_int4(mi[0], mi[1], mi[2], mi[3]);
    }
}

// ---------------- Kernel 2: vx = xr Vw^T + Vb ; ux = xr Uw^T + Ub -------------
// block: 256 threads, 128 rows x 64 out-cols. k chunks of 32.
__global__ __launch_bounds__(256) void k_vxux(const float* __restrict__ x,
        const float* __restrict__ Vw, const float* __restrict__ Vb,
        const float* __restrict__ Uw, const float* __restrict__ Ub,
        float* __restrict__ vx, float* __restrict__ ux) {
    __shared__ float A_l[32 * 128];   // [k][row]
    __shared__ float W_l[32 * 64];    // [k][d]
    const int bx  = blockIdx.x;
    const int rt  = bx >> 2;
    const int ct  = bx & 3;
    const int tid = threadIdx.x;
    const int rg  = tid >> 4;         // 0..15 -> rows rg*8..+7
    const int cg  = tid & 15;         // cols cg*4..+3
    const int r0  = rt << 7;
    const int n   = r0 >> 9;
    const int xb  = xbase_n(n);
    const int tb  = r0 & 511;
    const bool isV = (ct < 2);
    const float* Wsrc = isV ? Vw : Uw;
    const int d0 = (ct & 1) << 6;

    float acc[8][4];
    #pragma unroll
    for (int i = 0; i < 8; ++i)
        #pragma unroll
        for (int j = 0; j < 4; ++j) acc[i][j] = 0.f;

    #pragma unroll 1
    for (int kc = 0; kc < 4; ++kc) {
        __syncthreads();
        #pragma unroll
        for (int p = 0; p < 4; ++p) {                  // A: 128 rows x 32 k
            int f4  = tid + (p << 8);                  // 0..1023
            int row = f4 >> 3;
            int kq  = f4 & 7;
            float4 v = *(const float4*)(x + xb + (tb + row) * (J_*C_)
                                        + (kc << 5) + (kq << 2));
            A_l[(kq*4+0)*128 + row] = v.x;
            A_l[(kq*4+1)*128 + row] = v.y;
            A_l[(kq*4+2)*128 + row] = v.z;
            A_l[(kq*4+3)*128 + row] = v.w;
        }
        #pragma unroll
        for (int p = 0; p < 2; ++p) {                  // W: 64 d x 32 k
            int f4 = tid + (p << 8);                   // 0..511
            int dl = f4 >> 3;
            int kq = f4 & 7;
            float4 v = *(const float4*)(Wsrc + (d0 + dl) * C_ + (kc << 5) + (kq << 2));
            W_l[(kq*4+0)*64 + dl] = v.x;
            W_l[(kq*4+1)*64 + dl] = v.y;
            W_l[(kq*4+2)*64 + dl] = v.z;
            W_l[(kq*4+3)*64 + dl] = v.w;
        }
        __syncthreads();
        #pragma unroll 4
        for (int kk = 0; kk < 32; ++kk) {
            float4 a0 = *(const float4*)&A_l[kk*128 + rg*8];
            float4 a1 = *(const float4*)&A_l[kk*128 + rg*8 + 4];
            float4 w  = *(const float4*)&W_l[kk*64 + cg*4];
            float av[8] = {a0.x,a0.y,a0.z,a0.w,a1.x,a1.y,a1.z,a1.w};
            float wv[4] = {w.x,w.y,w.z,w.w};
            #pragma unroll
            for (int i = 0; i < 8; ++i)
                #pragma unroll
                for (int j = 0; j < 4; ++j)
                    acc[i][j] = fmaf(av[i], wv[j], acc[i][j]);
        }
    }

    const float* bias = isV ? Vb : Ub;
    float4 bb = *(const float4*)(bias + d0 + cg*4);
    float* dst = isV ? vx : ux;
    #pragma unroll
    for (int i = 0; i < 8; ++i) {
        int r = r0 + rg*8 + i;
        float4 o;
        o.x = acc[i][0] + bb.x; o.y = acc[i][1] + bb.y;
        o.z = acc[i][2] + bb.z; o.w = acc[i][3] + bb.w;
        *(float4*)(dst + (size_t)r*C_ + d0 + cg*4) = o;
    }
}

// ---------------- Kernel 3: out_pre = 0.25*sum(vx[nbr]) + ux ; BN partial sums -
__global__ __launch_bounds__(256) void k_agg(const float* __restrict__ vx,
        float* __restrict__ ux, const int* __restrict__ nbr,
        float* __restrict__ stats) {
    __shared__ float red[256 * 8];
    const int tid = threadIdx.x;
    const int r0  = blockIdx.x << 6;
    const int cq  = tid & 31;
    const int rl  = tid >> 5;
    float s0=0,s1=0,s2=0,s3=0, q0=0,q1=0,q2=0,q3=0;
    const float4* vr = (const float4*)vx;
    for (int p = 0; p < 8; ++p) {
        int r = r0 + (p << 3) + rl;
        int4 nb = *(const int4*)(nbr + ((size_t)r << 2));
        int base = (r >> 9) << 9;
        float4 a  = *(const float4*)(ux + (size_t)r*C_ + (cq << 2));
        float4 v0 = vr[(size_t)(base + nb.x)*32 + cq];
        float4 v1 = vr[(size_t)(base + nb.y)*32 + cq];
        float4 v2 = vr[(size_t)(base + nb.z)*32 + cq];
        float4 v3 = vr[(size_t)(base + nb.w)*32 + cq];
        a.x += 0.25f * (v0.x + v1.x + v2.x + v3.x);
        a.y += 0.25f * (v0.y + v1.y + v2.y + v3.y);
        a.z += 0.25f * (v0.z + v1.z + v2.z + v3.z);
        a.w += 0.25f * (v0.w + v1.w + v2.w + v3.w);
        *(float4*)(ux + (size_t)r*C_ + (cq << 2)) = a;
        s0 += a.x; s1 += a.y; s2 += a.z; s3 += a.w;
        q0 += a.x*a.x; q1 += a.y*a.y; q2 += a.z*a.z; q3 += a.w*a.w;
    }
    red[tid*8+0]=s0; red[tid*8+1]=s1; red[tid*8+2]=s2; red[tid*8+3]=s3;
    red[tid*8+4]=q0; red[tid*8+5]=q1; red[tid*8+6]=q2; red[tid*8+7]=q3;
    __syncthreads();
    if (tid < 32) {
        for (int g = 1; g < 8; ++g) {
            int o = (tid + 32*g)*8;
            s0 += red[o+0]; s1 += red[o+1]; s2 += red[o+2]; s3 += red[o+3];
            q0 += red[o+4]; q1 += red[o+5]; q2 += red[o+6]; q3 += red[o+7];
        }
        int c0 = tid*4;
        atomicAdd(&stats[c0+0], s0); atomicAdd(&stats[c0+1], s1);
        atomicAdd(&stats[c0+2], s2); atomicAdd(&stats[c0+3], s3);
        atomicAdd(&stats[128+c0+0], q0); atomicAdd(&stats[128+c0+1], q1);
        atomicAdd(&stats[128+c0+2], q2); atomicAdd(&stats[128+c0+3], q3);
    }
}

// ---------------- Kernel 4: BN normalize + residual + ReLU + transpose --------
__global__ __launch_bounds__(256) void k_fin(const float* __restrict__ x,
        const float* __restrict__ pre, const float* __restrict__ stats,
        const float* __restrict__ gamma, const float* __restrict__ beta,
        float* __restrict__ out) {
    const int id = blockIdx.x * 256 + threadIdx.x;   // float4 id
    const int r  = id >> 5;
    const int c0 = (id & 31) << 2;
    const float inv = 1.0f / (float)R_;
    float4 s  = *(const float4*)(stats + c0);
    float4 sq = *(const float4*)(stats + 128 + c0);
    float4 g  = *(const float4*)(gamma + c0);
    float4 bt = *(const float4*)(beta + c0);
    float m0 = s.x*inv, m1 = s.y*inv, m2 = s.z*inv, m3 = s.w*inv;
    float sc0 = g.x * rsqrtf(sq.x*inv - m0*m0 + BN_EPS);
    float sc1 = g.y * rsqrtf(sq.y*inv - m1*m1 + BN_EPS);
    float sc2 = g.z * rsqrtf(sq.z*inv - m2*m2 + BN_EPS);
    float sc3 = g.w * rsqrtf(sq.w*inv - m3*m3 + BN_EPS);
    float sh0 = bt.x - m0*sc0, sh1 = bt.y - m1*sc1;
    float sh2 = bt.z - m2*sc2, sh3 = bt.w - m3*sc3;
    int n = r >> 9, t = r & 511;
    int off = xbase_n(n) + t*(J_*C_) + c0;
    float4 xv = *(const float4*)(x + off);
    float4 p  = *(const float4*)(pre + (size_t)r*C_ + c0);
    float4 y;
    y.x = xv.x + p.x*sc0 + sh0; y.y = xv.y + p.y*sc1 + sh1;
    y.z = xv.z + p.z*sc2 + sh2; y.w = xv.w + p.w*sc3 + sh3;
    y.x = y.x > 0.f ? y.x : 0.f; y.y = y.y > 0.f ? y.y : 0.f;
    y.z = y.z > 0.f ? y.z : 0.f; y.w = y.w > 0.f ? y.w : 0.f;
    *(float4*)(out + off) = y;
}

extern "C" void kernel_launch(void* const* d_in, const int* in_sizes, int n_in,
                              void* d_out, int out_size, void* d_ws, size_t ws_size,
                              hipStream_t stream) {
    const float* x     = (const float*)d_in[0];
    const float* Uw    = (const float*)d_in[1];
    const float* Ub    = (const float*)d_in[2];
    const float* Vw    = (const float*)d_in[3];
    const float* Vb    = (const float*)d_in[4];
    const float* gamma = (const float*)d_in[5];
    const float* beta  = (const float*)d_in[6];
    float* out = (float*)d_out;

    // workspace layout: ux/out_pre (R*C f32) | nbr (R*4 i32) | stats (256 f32)
    float* ux    = (float*)d_ws;
    int*   nbr   = (int*)(ux + (size_t)R_ * C_);
    float* stats = (float*)(nbr + (size_t)R_ * 4);
    float* vx    = out;   // d_out doubles as vx scratch; overwritten by k_fin

    hipMemsetAsync(stats, 0, 256 * sizeof(float), stream);
    k_sim_topk<<<N_ * 16, 256, 0, stream>>>(x, nbr);
    k_vxux<<<(R_ / 128) * 4, 256, 0, stream>>>(x, Vw, Vb, Uw, Ub, vx, ux);
    k_agg<<<R_ / 64, 256, 0, stream>>>(vx, ux, nbr, stats);
    k_fin<<<(R_ * 32) / 256, 256, 0, stream>>>(x, ux, stats, gamma, beta, out);
}

// Round 3
// 495.389 us; speedup vs baseline: 61.9374x; 1.0395x over previous
//
#include <hip/hip_runtime.h>
#include <math.h>

#define T_ 512
#define J_ 24
#define B_ 8
#define C_ 128
#define N_ (B_*J_)        // 192
#define R_ (N_*T_)        // 98304
#define JC_ (J_*C_)       // 3072
#define BN_EPS 1e-5f

// x layout: (B, T, J, C). Row r = n*T + t with n = b*J + j.
__device__ __forceinline__ int xbase_n(int n) {
    int b = n / J_;
    int j = n - b * J_;
    return (b * T_ * J_ + j) * C_;     // add t*(J_*C_) + c
}

// keep v[0] >= v[1] >= v[2] >= v[3]
__device__ __forceinline__ void ins4(float (&v)[4], int (&ix)[4], float nv, int ni) {
    if (nv > v[3]) {
        if (nv > v[1]) {
            if (nv > v[0]) {
                v[3]=v[2]; ix[3]=ix[2]; v[2]=v[1]; ix[2]=ix[1];
                v[1]=v[0]; ix[1]=ix[0]; v[0]=nv; ix[0]=ni;
            } else {
                v[3]=v[2]; ix[3]=ix[2]; v[2]=v[1]; ix[2]=ix[1];
                v[1]=nv; ix[1]=ni;
            }
        } else {
            if (nv > v[2]) { v[3]=v[2]; ix[3]=ix[2]; v[2]=nv; ix[2]=ni; }
            else           { v[3]=nv; ix[3]=ni; }
        }
    }
}

// ---------------- Kernel 1: sim = X_n X_n^T rowwise top-4 neighbor indices ----
// Block: 256 thr = 8 tg x 32 sg. 64 t-rows/block, s in 2 halves of 256.
// Thread tile: 8 rows (tg*8..+7) x 8 cols ({sg*4..+3} and {128+sg*4..+3}).
// LDS: A_l [k(32)][row(64)], B_l [k(32)][s(256)], both XOR-swizzled:
//   store/read 16B-chunk index ^= (k>>2)  -> conflict-free b128 both ways.
__global__ __launch_bounds__(256) void k_sim_topk(const float* __restrict__ x,
                                                  int* __restrict__ nbr) {
    __shared__ float A_l[32 * 64];     // 8 KB
    __shared__ float B_l[32 * 256];    // 32 KB
    const int bx  = blockIdx.x;
    const int n   = bx >> 3;
    const int t0  = (bx & 7) << 6;
    const int tid = threadIdx.x;
    const int xb  = xbase_n(n);
    const int tg  = tid >> 5;          // 0..7
    const int sg  = tid & 31;          // 0..31

    float tv[8][4]; int ti[8][4];
    #pragma unroll
    for (int i = 0; i < 8; ++i)
        #pragma unroll
        for (int q = 0; q < 4; ++q) { tv[i][q] = -INFINITY; ti[i][q] = 0; }

    #pragma unroll 1
    for (int half = 0; half < 2; ++half) {
        const int s0 = half << 8;
        float acc[8][8];
        #pragma unroll
        for (int i = 0; i < 8; ++i)
            #pragma unroll
            for (int j = 0; j < 8; ++j) acc[i][j] = 0.f;

        #pragma unroll 1
        for (int kc = 0; kc < 4; ++kc) {
            __syncthreads();
            // ---- stage A: 64 rows x 32 k, reg-transposed, swizzled b128 stores
            if (tid < 128) {
                int rchunk = tid >> 3, kq = tid & 7;
                const float* src = x + xb + (t0 + rchunk*4)*JC_ + (kc<<5) + (kq<<2);
                float4 v0 = *(const float4*)(src);
                float4 v1 = *(const float4*)(src + JC_);
                float4 v2 = *(const float4*)(src + 2*JC_);
                float4 v3 = *(const float4*)(src + 3*JC_);
                int cs = (rchunk ^ kq) << 2;
                *(float4*)&A_l[(kq*4+0)*64 + cs] = make_float4(v0.x,v1.x,v2.x,v3.x);
                *(float4*)&A_l[(kq*4+1)*64 + cs] = make_float4(v0.y,v1.y,v2.y,v3.y);
                *(float4*)&A_l[(kq*4+2)*64 + cs] = make_float4(v0.z,v1.z,v2.z,v3.z);
                *(float4*)&A_l[(kq*4+3)*64 + cs] = make_float4(v0.w,v1.w,v2.w,v3.w);
            }
            // ---- stage B: 256 s-rows x 32 k, same pattern, 2 groups/thread
            #pragma unroll
            for (int p = 0; p < 2; ++p) {
                int slot = tid + (p << 8);
                int schunk = slot >> 3, kq = slot & 7;
                const float* src = x + xb + (s0 + schunk*4)*JC_ + (kc<<5) + (kq<<2);
                float4 v0 = *(const float4*)(src);
                float4 v1 = *(const float4*)(src + JC_);
                float4 v2 = *(const float4*)(src + 2*JC_);
                float4 v3 = *(const float4*)(src + 3*JC_);
                int cs = (schunk ^ kq) << 2;
                *(float4*)&B_l[(kq*4+0)*256 + cs] = make_float4(v0.x,v1.x,v2.x,v3.x);
                *(float4*)&B_l[(kq*4+1)*256 + cs] = make_float4(v0.y,v1.y,v2.y,v3.y);
                *(float4*)&B_l[(kq*4+2)*256 + cs] = make_float4(v0.z,v1.z,v2.z,v3.z);
                *(float4*)&B_l[(kq*4+3)*256 + cs] = make_float4(v0.w,v1.w,v2.w,v3.w);
            }
            __syncthreads();
            #pragma unroll 2
            for (int kk = 0; kk < 32; ++kk) {
                const int h = kk >> 2;
                float4 alo = *(const float4*)&A_l[kk*64  + ((((tg<<1)  ) ^ h) << 2)];
                float4 ahi = *(const float4*)&A_l[kk*64  + ((((tg<<1)|1) ^ h) << 2)];
                float4 blo = *(const float4*)&B_l[kk*256 + ((sg ^ h) << 2)];
                float4 bhi = *(const float4*)&B_l[kk*256 + 128 + ((sg ^ h) << 2)];
                float av[8] = {alo.x,alo.y,alo.z,alo.w, ahi.x,ahi.y,ahi.z,ahi.w};
                float bv[8] = {blo.x,blo.y,blo.z,blo.w, bhi.x,bhi.y,bhi.z,bhi.w};
                #pragma unroll
                for (int i = 0; i < 8; ++i)
                    #pragma unroll
                    for (int j = 0; j < 8; ++j)
                        acc[i][j] = fmaf(av[i], bv[j], acc[i][j]);
            }
        }
        // fold this half into running per-row top4 (indices are absolute s)
        #pragma unroll
        for (int i = 0; i < 8; ++i) {
            #pragma unroll
            for (int j = 0; j < 4; ++j)
                ins4(tv[i], ti[i], acc[i][j], s0 + sg*4 + j);
            #pragma unroll
            for (int j = 4; j < 8; ++j)
                ins4(tv[i], ti[i], acc[i][j], s0 + 128 + sg*4 + (j-4));
        }
    }

    // ---- merge: 2 shfl_xor steps (sg bits 0,1), then LDS, then per-row final
    __syncthreads();                    // everyone done reading B_l
    #pragma unroll
    for (int i = 0; i < 8; ++i) {
        #pragma unroll
        for (int st = 1; st <= 2; st <<= 1) {
            float rv[4]; int ri[4];
            #pragma unroll
            for (int q = 0; q < 4; ++q) {
                rv[q] = __shfl_xor(tv[i][q], st);
                ri[q] = __shfl_xor(ti[i][q], st);
            }
            #pragma unroll
            for (int q = 0; q < 4; ++q) ins4(tv[i], ti[i], rv[q], ri[q]);
        }
    }
    float* scv = B_l;                   // 2048 floats
    int*   sci = (int*)(B_l + 2048);    // 2048 ints
    if ((sg & 3) == 0) {
        int g = sg >> 2;                // 0..7
        #pragma unroll
        for (int i = 0; i < 8; ++i) {
            int row = tg*8 + i;
            #pragma unroll
            for (int q = 0; q < 4; ++q) {
                scv[(row*8 + g)*4 + q] = tv[i][q];
                sci[(row*8 + g)*4 + q] = ti[i][q];
            }
        }
    }
    __syncthreads();
    if (tid < 64) {
        float mv[4]; int mi[4];
        #pragma unroll
        for (int q = 0; q < 4; ++q) { mv[q] = -INFINITY; mi[q] = 0; }
        for (int g = 0; g < 8; ++g)
            #pragma unroll
            for (int q = 0; q < 4; ++q)
                ins4(mv, mi, scv[(tid*8 + g)*4 + q], sci[(tid*8 + g)*4 + q]);
        int r = n*T_ + t0 + tid;
        *(int4*)(nbr + (size_t)r*4) = make_int4(mi[0], mi[1], mi[2], mi[3]);
    }
}

// ---------------- Kernel 2: vx = xr Vw^T + Vb ; ux = xr Uw^T + Ub -------------
// Block: 256 thr = 16 rg x 16 cg; tile 128 rows x 128 d; one block per {V,U}.
// A_l [k(32)][row(128)], W_l [k(32)][d(128)], swizzled as in k_sim.
__global__ __launch_bounds__(256) void k_vxux(const float* __restrict__ x,
        const float* __restrict__ Vw, const float* __restrict__ Vb,
        const float* __restrict__ Uw, const float* __restrict__ Ub,
        float* __restrict__ vx, float* __restrict__ ux) {
    __shared__ float A_l[32 * 128];    // 16 KB
    __shared__ float W_l[32 * 128];    // 16 KB
    const int bx  = blockIdx.x;
    const int rt  = bx >> 1;
    const int isU = bx & 1;
    const int tid = threadIdx.x;
    const int rg  = tid >> 4;          // 0..15 -> rows rg*8..+7
    const int cg  = tid & 15;          // 0..15 -> cols cg*8..+7
    const int r0  = rt << 7;
    const int xb  = xbase_n(r0 >> 9);
    const int tb  = r0 & 511;
    const float* Wsrc = isU ? Uw : Vw;

    float acc[8][8];
    #pragma unroll
    for (int i = 0; i < 8; ++i)
        #pragma unroll
        for (int j = 0; j < 8; ++j) acc[i][j] = 0.f;

    const int rchunk = tid >> 3, kq = tid & 7;   // staging roles
    #pragma unroll 1
    for (int kc = 0; kc < 4; ++kc) {
        __syncthreads();
        {   // stage A: 128 rows x 32 k
            const float* src = x + xb + (tb + rchunk*4)*JC_ + (kc<<5) + (kq<<2);
            float4 v0 = *(const float4*)(src);
            float4 v1 = *(const float4*)(src + JC_);
            float4 v2 = *(const float4*)(src + 2*JC_);
            float4 v3 = *(const float4*)(src + 3*JC_);
            int cs = (rchunk ^ kq) << 2;
            *(float4*)&A_l[(kq*4+0)*128 + cs] = make_float4(v0.x,v1.x,v2.x,v3.x);
            *(float4*)&A_l[(kq*4+1)*128 + cs] = make_float4(v0.y,v1.y,v2.y,v3.y);
            *(float4*)&A_l[(kq*4+2)*128 + cs] = make_float4(v0.z,v1.z,v2.z,v3.z);
            *(float4*)&A_l[(kq*4+3)*128 + cs] = make_float4(v0.w,v1.w,v2.w,v3.w);
        }
        {   // stage W: 128 d x 32 k
            const float* src = Wsrc + (rchunk*4)*C_ + (kc<<5) + (kq<<2);
            float4 v0 = *(const float4*)(src);
            float4 v1 = *(const float4*)(src + C_);
            float4 v2 = *(const float4*)(src + 2*C_);
            float4 v3 = *(const float4*)(src + 3*C_);
            int cs = (rchunk ^ kq) << 2;
            *(float4*)&W_l[(kq*4+0)*128 + cs] = make_float4(v0.x,v1.x,v2.x,v3.x);
            *(float4*)&W_l[(kq*4+1)*128 + cs] = make_float4(v0.y,v1.y,v2.y,v3.y);
            *(float4*)&W_l[(kq*4+2)*128 + cs] = make_float4(v0.z,v1.z,v2.z,v3.z);
            *(float4*)&W_l[(kq*4+3)*128 + cs] = make_float4(v0.w,v1.w,v2.w,v3.w);
        }
        __syncthreads();
        #pragma unroll 2
        for (int kk = 0; kk < 32; ++kk) {
            const int h = kk >> 2;
            float4 alo = *(const float4*)&A_l[kk*128 + ((((rg<<1)  ) ^ h) << 2)];
            float4 ahi = *(const float4*)&A_l[kk*128 + ((((rg<<1)|1) ^ h) << 2)];
            float4 wlo = *(const float4*)&W_l[kk*128 + ((((cg<<1)  ) ^ h) << 2)];
            float4 whi = *(const float4*)&W_l[kk*128 + ((((cg<<1)|1) ^ h) << 2)];
            float av[8] = {alo.x,alo.y,alo.z,alo.w, ahi.x,ahi.y,ahi.z,ahi.w};
            float wv[8] = {wlo.x,wlo.y,wlo.z,wlo.w, whi.x,whi.y,whi.z,whi.w};
            #pragma unroll
            for (int i = 0; i < 8; ++i)
                #pragma unroll
                for (int j = 0; j < 8; ++j)
                    acc[i][j] = fmaf(av[i], wv[j], acc[i][j]);
        }
    }

    const float* bias = isU ? Ub : Vb;
    float* dst = isU ? ux : vx;
    float4 b0 = *(const float4*)(bias + cg*8);
    float4 b1 = *(const float4*)(bias + cg*8 + 4);
    #pragma unroll
    for (int i = 0; i < 8; ++i) {
        int r = r0 + rg*8 + i;
        float4 o0, o1;
        o0.x = acc[i][0]+b0.x; o0.y = acc[i][1]+b0.y;
        o0.z = acc[i][2]+b0.z; o0.w = acc[i][3]+b0.w;
        o1.x = acc[i][4]+b1.x; o1.y = acc[i][5]+b1.y;
        o1.z = acc[i][6]+b1.z; o1.w = acc[i][7]+b1.w;
        *(float4*)(dst + (size_t)r*C_ + cg*8)     = o0;
        *(float4*)(dst + (size_t)r*C_ + cg*8 + 4) = o1;
    }
}

// ---------------- Kernel 3: out_pre = 0.25*sum(vx[nbr]) + ux ; BN partial sums -
__global__ __launch_bounds__(256) void k_agg(const float* __restrict__ vx,
        float* __restrict__ ux, const int* __restrict__ nbr,
        float* __restrict__ stats) {
    __shared__ float red[256 * 8];
    const int tid = threadIdx.x;
    const int r0  = blockIdx.x << 6;
    const int cq  = tid & 31;
    const int rl  = tid >> 5;
    float s0=0,s1=0,s2=0,s3=0, q0=0,q1=0,q2=0,q3=0;
    const float4* vr = (const float4*)vx;
    for (int p = 0; p < 8; ++p) {
        int r = r0 + (p << 3) + rl;
        int4 nb = *(const int4*)(nbr + ((size_t)r << 2));
        int base = (r >> 9) << 9;
        float4 a  = *(const float4*)(ux + (size_t)r*C_ + (cq << 2));
        float4 v0 = vr[(size_t)(base + nb.x)*32 + cq];
        float4 v1 = vr[(size_t)(base + nb.y)*32 + cq];
        float4 v2 = vr[(size_t)(base + nb.z)*32 + cq];
        float4 v3 = vr[(size_t)(base + nb.w)*32 + cq];
        a.x += 0.25f * (v0.x + v1.x + v2.x + v3.x);
        a.y += 0.25f * (v0.y + v1.y + v2.y + v3.y);
        a.z += 0.25f * (v0.z + v1.z + v2.z + v3.z);
        a.w += 0.25f * (v0.w + v1.w + v2.w + v3.w);
        *(float4*)(ux + (size_t)r*C_ + (cq << 2)) = a;
        s0 += a.x; s1 += a.y; s2 += a.z; s3 += a.w;
        q0 += a.x*a.x; q1 += a.y*a.y; q2 += a.z*a.z; q3 += a.w*a.w;
    }
    red[tid*8+0]=s0; red[tid*8+1]=s1; red[tid*8+2]=s2; red[tid*8+3]=s3;
    red[tid*8+4]=q0; red[tid*8+5]=q1; red[tid*8+6]=q2; red[tid*8+7]=q3;
    __syncthreads();
    if (tid < 32) {
        for (int g = 1; g < 8; ++g) {
            int o = (tid + 32*g)*8;
            s0 += red[o+0]; s1 += red[o+1]; s2 += red[o+2]; s3 += red[o+3];
            q0 += red[o+4]; q1 += red[o+5]; q2 += red[o+6]; q3 += red[o+7];
        }
        int c0 = tid*4;
        atomicAdd(&stats[c0+0], s0); atomicAdd(&stats[c0+1], s1);
        atomicAdd(&stats[c0+2], s2); atomicAdd(&stats[c0+3], s3);
        atomicAdd(&stats[128+c0+0], q0); atomicAdd(&stats[128+c0+1], q1);
        atomicAdd(&stats[128+c0+2], q2); atomicAdd(&stats[128+c0+3], q3);
    }
}

// ---------------- Kernel 4: BN normalize + residual + ReLU + transpose --------
__global__ __launch_bounds__(256) void k_fin(const float* __restrict__ x,
        const float* __restrict__ pre, const float* __restrict__ stats,
        const float* __restrict__ gamma, const float* __restrict__ beta,
        float* __restrict__ out) {
    const int id = blockIdx.x * 256 + threadIdx.x;   // float4 id
    const int r  = id >> 5;
    const int c0 = (id & 31) << 2;
    const float inv = 1.0f / (float)R_;
    float4 s  = *(const float4*)(stats + c0);
    float4 sq = *(const float4*)(stats + 128 + c0);
    float4 g  = *(const float4*)(gamma + c0);
    float4 bt = *(const float4*)(beta + c0);
    float m0 = s.x*inv, m1 = s.y*inv, m2 = s.z*inv, m3 = s.w*inv;
    float sc0 = g.x * rsqrtf(sq.x*inv - m0*m0 + BN_EPS);
    float sc1 = g.y * rsqrtf(sq.y*inv - m1*m1 + BN_EPS);
    float sc2 = g.z * rsqrtf(sq.z*inv - m2*m2 + BN_EPS);
    float sc3 = g.w * rsqrtf(sq.w*inv - m3*m3 + BN_EPS);
    float sh0 = bt.x - m0*sc0, sh1 = bt.y - m1*sc1;
    float sh2 = bt.z - m2*sc2, sh3 = bt.w - m3*sc3;
    int n = r >> 9, t = r & 511;
    int off = xbase_n(n) + t*(J_*C_) + c0;
    float4 xv = *(const float4*)(x + off);
    float4 p  = *(const float4*)(pre + (size_t)r*C_ + c0);
    float4 y;
    y.x = xv.x + p.x*sc0 + sh0; y.y = xv.y + p.y*sc1 + sh1;
    y.z = xv.z + p.z*sc2 + sh2; y.w = xv.w + p.w*sc3 + sh3;
    y.x = y.x > 0.f ? y.x : 0.f; y.y = y.y > 0.f ? y.y : 0.f;
    y.z = y.z > 0.f ? y.z : 0.f; y.w = y.w > 0.f ? y.w : 0.f;
    *(float4*)(out + off) = y;
}

extern "C" void kernel_launch(void* const* d_in, const int* in_sizes, int n_in,
                              void* d_out, int out_size, void* d_ws, size_t ws_size,
                              hipStream_t stream) {
    const float* x     = (const float*)d_in[0];
    const float* Uw    = (const float*)d_in[1];
    const float* Ub    = (const float*)d_in[2];
    const float* Vw    = (const float*)d_in[3];
    const float* Vb    = (const float*)d_in[4];
    const float* gamma = (const float*)d_in[5];
    const float* beta  = (const float*)d_in[6];
    float* out = (float*)d_out;

    // workspace layout: ux/out_pre (R*C f32) | nbr (R*4 i32) | stats (256 f32)
    float* ux    = (float*)d_ws;
    int*   nbr   = (int*)(ux + (size_t)R_ * C_);
    float* stats = (float*)(nbr + (size_t)R_ * 4);
    float* vx    = out;   // d_out doubles as vx scratch; overwritten by k_fin

    hipMemsetAsync(stats, 0, 256 * sizeof(float), stream);
    k_sim_topk<<<N_ * 8, 256, 0, stream>>>(x, nbr);
    k_vxux<<<(R_ / 128) * 2, 256, 0, stream>>>(x, Vw, Vb, Uw, Ub, vx, ux);
    k_agg<<<R_ / 64, 256, 0, stream>>>(vx, ux, nbr, stats);
    k_fin<<<(R_ * 32) / 256, 256, 0, stream>>>(x, ux, stats, gamma, beta, out);
}

// Round 4
// 392.535 us; speedup vs baseline: 78.1666x; 1.2620x over previous
//
#include <hip/hip_runtime.h>
#include <math.h>

#define T_ 512
#define J_ 24
#define B_ 8
#define C_ 128
#define N_ (B_*J_)        // 192
#define R_ (N_*T_)        // 98304
#define JC_ (J_*C_)       // 3072
#define BN_EPS 1e-5f

typedef _Float16 half_t;
typedef half_t half8 __attribute__((ext_vector_type(8)));
typedef half_t half4h __attribute__((ext_vector_type(4)));
typedef float f32x4 __attribute__((ext_vector_type(4)));

__device__ __forceinline__ f32x4 mfma16(half8 a, half8 b, f32x4 c) {
    return __builtin_amdgcn_mfma_f32_16x16x32_f16(a, b, c, 0, 0, 0);
}

// x layout: (B, T, J, C). Row r = n*T + t with n = b*J + j.
__device__ __forceinline__ int xbase_n(int n) {
    int b = n / J_;
    int j = n - b * J_;
    return (b * T_ * J_ + j) * C_;     // add t*(J_*C_) + c
}

__device__ __forceinline__ void split2(float x, half_t& h, half_t& l) {
    half_t hh = (half_t)x;
    h = hh;
    l = (half_t)(x - (float)hh);
}

// keep v[0] >= v[1] >= v[2] >= v[3]
__device__ __forceinline__ void ins4(float (&v)[4], int (&ix)[4], float nv, int ni) {
    if (nv > v[3]) {
        if (nv > v[1]) {
            if (nv > v[0]) {
                v[3]=v[2]; ix[3]=ix[2]; v[2]=v[1]; ix[2]=ix[1];
                v[1]=v[0]; ix[1]=ix[0]; v[0]=nv; ix[0]=ni;
            } else {
                v[3]=v[2]; ix[3]=ix[2]; v[2]=v[1]; ix[2]=ix[1];
                v[1]=nv; ix[1]=ni;
            }
        } else {
            if (nv > v[2]) { v[3]=v[2]; ix[3]=ix[2]; v[2]=nv; ix[2]=ni; }
            else           { v[3]=nv; ix[3]=ni; }
        }
    }
}

// ---------------- Kernel 1: sim = X_n X_n^T via fp16-split MFMA, top-4 -------
// Block: 512 thr = 8 waves (wr=w>>2 t-half, wc=w&3 s-quarter).
// Block tile: 128 t x 512 s. Wave tile: 64 t x 128 s = 4 mi x 8 ni 16x16 tiles.
// LDS: Ah/Al [128t][128k] fp16 (64KB) + Bh/Bl [512s][32k] fp16 (64KB) = 128KB,
// 16B-chunk XOR swizzle. After compute, LDS is reused as a 64x512 f32 dump
// buffer for row-wise top-4 scan (two rounds of 64 rows).
__global__ __launch_bounds__(512, 2) void k_sim_topk(const float* __restrict__ x,
                                                     int* __restrict__ nbr) {
    __shared__ float4 lds_raw[8192];            // 128 KB
    half_t* Ah = (half_t*)lds_raw;              // [128][128]
    half_t* Al = Ah + 128*128;
    half_t* Bh = Al + 128*128;                  // [512][32]
    half_t* Bl = Bh + 512*32;
    float*  dump = (float*)lds_raw;             // [64][512] overlay (post-MFMA)

    // XCD-contiguous remap: 768 blocks, 8 XCDs -> the 4 blocks of one n share an XCD L2
    const int bx = (int)blockIdx.x;
    const int wg = (bx & 7) * 96 + (bx >> 3);
    const int n  = wg >> 2;
    const int t0 = (wg & 3) << 7;
    const int tid = threadIdx.x;
    const int xb = xbase_n(n);

    // ---- stage A: 128 t x 128 k fp32 -> fp16 h/l (chunk' = chunk ^ (row&15))
    #pragma unroll
    for (int p = 0; p < 8; ++p) {
        int f4  = tid + (p << 9);       // 0..4095
        int row = f4 >> 5;              // 32 float4 per row
        int kq  = f4 & 31;
        float4 v = *(const float4*)(x + xb + (t0 + row) * JC_ + (kq << 2));
        int off = row * 128 + (((kq >> 1) ^ (row & 15)) << 3) + ((kq & 1) << 2);
        half_t h0,l0,h1,l1,h2,l2,h3,l3;
        split2(v.x,h0,l0); split2(v.y,h1,l1); split2(v.z,h2,l2); split2(v.w,h3,l3);
        *(half4h*)&Ah[off] = (half4h){h0,h1,h2,h3};
        *(half4h*)&Al[off] = (half4h){l0,l1,l2,l3};
    }

    const int lane = tid & 63;
    const int w    = tid >> 6;
    const int wr   = w >> 2;            // 0..1
    const int wc   = w & 3;             // 0..3
    const int lm   = lane & 15;
    const int lh   = lane >> 4;         // 0..3

    f32x4 acc[4][8];
    #pragma unroll
    for (int mi = 0; mi < 4; ++mi)
        #pragma unroll
        for (int ni = 0; ni < 8; ++ni) acc[mi][ni] = (f32x4){0.f,0.f,0.f,0.f};

    #pragma unroll 1
    for (int kc = 0; kc < 4; ++kc) {
        __syncthreads();                // A staged / prev B reads done
        // ---- stage B chunk: 512 s x 32 k (chunk' = chunk ^ (srow&3))
        #pragma unroll
        for (int p = 0; p < 8; ++p) {
            int f4   = tid + (p << 9);  // 0..4095
            int srow = f4 >> 3;         // 8 float4 per row
            int kq   = f4 & 7;
            float4 v = *(const float4*)(x + xb + srow * JC_ + (kc << 5) + (kq << 2));
            int off = srow * 32 + (((kq >> 1) ^ (srow & 3)) << 3) + ((kq & 1) << 2);
            half_t h0,l0,h1,l1,h2,l2,h3,l3;
            split2(v.x,h0,l0); split2(v.y,h1,l1); split2(v.z,h2,l2); split2(v.w,h3,l3);
            *(half4h*)&Bh[off] = (half4h){h0,h1,h2,h3};
            *(half4h*)&Bl[off] = (half4h){l0,l1,l2,l3};
        }
        __syncthreads();

        half8 a_h[4], a_l[4];
        #pragma unroll
        for (int mi = 0; mi < 4; ++mi) {
            int row = (wr << 6) + (mi << 4) + lm;
            int off = row * 128 + ((((kc << 2) + lh) ^ (row & 15)) << 3);
            a_h[mi] = *(half8*)&Ah[off];
            a_l[mi] = *(half8*)&Al[off];
        }
        #pragma unroll
        for (int ni = 0; ni < 8; ++ni) {
            int srow = (wc << 7) + (ni << 4) + lm;
            int off = srow * 32 + ((lh ^ (srow & 3)) << 3);
            half8 bh = *(half8*)&Bh[off];
            half8 bl = *(half8*)&Bl[off];
            #pragma unroll
            for (int mi = 0; mi < 4; ++mi) {
                acc[mi][ni] = mfma16(a_h[mi], bh, acc[mi][ni]);
                acc[mi][ni] = mfma16(a_l[mi], bh, acc[mi][ni]);
                acc[mi][ni] = mfma16(a_h[mi], bl, acc[mi][ni]);
            }
        }
    }

    // ---- top-4: dump 64 rows at a time (f32, col-swizzled), scan, shfl-merge
    __syncthreads();
    #pragma unroll 1
    for (int dr = 0; dr < 2; ++dr) {
        if (wr == dr) {
            #pragma unroll
            for (int mi = 0; mi < 4; ++mi)
                #pragma unroll
                for (int ni = 0; ni < 8; ++ni) {
                    int col = (wc << 7) + (ni << 4) + lm;
                    #pragma unroll
                    for (int q = 0; q < 4; ++q) {
                        int rl = (mi << 4) + (lh << 2) + q;          // 0..63
                        dump[rl * 512 + (col ^ ((rl & 15) << 2))] = acc[mi][ni][q];
                    }
                }
        }
        __syncthreads();
        {
            int rl  = tid >> 3;          // 0..63, 8 threads per row
            int sub = tid & 7;
            int sw  = (rl & 15) << 2;
            float mv[4]; int mi4[4];
            mv[0]=mv[1]=mv[2]=mv[3] = -INFINITY;
            mi4[0]=mi4[1]=mi4[2]=mi4[3] = 0;
            #pragma unroll 4
            for (int j = 0; j < 64; ++j) {
                int c = sub + (j << 3);
                ins4(mv, mi4, dump[rl * 512 + (c ^ sw)], c);
            }
            #pragma unroll
            for (int st = 1; st <= 4; st <<= 1) {
                float rv[4]; int ri[4];
                #pragma unroll
                for (int q = 0; q < 4; ++q) {
                    rv[q] = __shfl_xor(mv[q], st);
                    ri[q] = __shfl_xor(mi4[q], st);
                }
                #pragma unroll
                for (int q = 0; q < 4; ++q) ins4(mv, mi4, rv[q], ri[q]);
            }
            if (sub == 0) {
                int r = n * T_ + t0 + (dr << 6) + rl;
                *(int4*)(nbr + (size_t)r * 4) = make_int4(mi4[0], mi4[1], mi4[2], mi4[3]);
            }
        }
        __syncthreads();
    }
}

// ---------------- Kernel 2: vx = xr Vw^T + Vb ; ux = xr Uw^T + Ub (MFMA) -----
// Block: 512 thr = 8 waves; 256 rows x 128 d, one of {V,U} per block.
// W (h/l) resident [128d][128k] 64KB; A chunk [256r][32k] h/l 32KB.
__global__ __launch_bounds__(512, 2) void k_vxux(const float* __restrict__ x,
        const float* __restrict__ Vw, const float* __restrict__ Vb,
        const float* __restrict__ Uw, const float* __restrict__ Ub,
        float* __restrict__ vx, float* __restrict__ ux) {
    __shared__ float4 lds_raw[6144];            // 96 KB
    half_t* Wh  = (half_t*)lds_raw;             // [128][128]
    half_t* Wl  = Wh + 128*128;
    half_t* Ach = Wl + 128*128;                 // [256][32]
    half_t* Acl = Ach + 256*32;

    const int bx  = (int)blockIdx.x;
    const int wg  = (bx & 7) * 96 + (bx >> 3);  // U/V of same rows share XCD
    const int isU = wg & 1;
    const int r0  = (wg >> 1) << 8;             // 256-row tile
    const int tid = threadIdx.x;
    const int xb  = xbase_n(r0 >> 9);
    const int tb  = r0 & 511;
    const float* Wsrc = isU ? Uw : Vw;

    // stage W: 128 d x 128 k
    #pragma unroll
    for (int p = 0; p < 8; ++p) {
        int f4  = tid + (p << 9);
        int row = f4 >> 5;
        int kq  = f4 & 31;
        float4 v = *(const float4*)(Wsrc + row * C_ + (kq << 2));
        int off = row * 128 + (((kq >> 1) ^ (row & 15)) << 3) + ((kq & 1) << 2);
        half_t h0,l0,h1,l1,h2,l2,h3,l3;
        split2(v.x,h0,l0); split2(v.y,h1,l1); split2(v.z,h2,l2); split2(v.w,h3,l3);
        *(half4h*)&Wh[off] = (half4h){h0,h1,h2,h3};
        *(half4h*)&Wl[off] = (half4h){l0,l1,l2,l3};
    }

    const int lane = tid & 63;
    const int w    = tid >> 6;          // wave owns rows [w*32, +32)
    const int lm   = lane & 15;
    const int lh   = lane >> 4;

    f32x4 acc[2][8];
    #pragma unroll
    for (int mi = 0; mi < 2; ++mi)
        #pragma unroll
        for (int ni = 0; ni < 8; ++ni) acc[mi][ni] = (f32x4){0.f,0.f,0.f,0.f};

    #pragma unroll 1
    for (int kc = 0; kc < 4; ++kc) {
        __syncthreads();
        // stage A chunk: 256 rows x 32 k
        #pragma unroll
        for (int p = 0; p < 4; ++p) {
            int f4  = tid + (p << 9);   // 0..2047
            int row = f4 >> 3;
            int kq  = f4 & 7;
            float4 v = *(const float4*)(x + xb + (tb + row) * JC_ + (kc << 5) + (kq << 2));
            int off = row * 32 + (((kq >> 1) ^ (row & 3)) << 3) + ((kq & 1) << 2);
            half_t h0,l0,h1,l1,h2,l2,h3,l3;
            split2(v.x,h0,l0); split2(v.y,h1,l1); split2(v.z,h2,l2); split2(v.w,h3,l3);
            *(half4h*)&Ach[off] = (half4h){h0,h1,h2,h3};
            *(half4h*)&Acl[off] = (half4h){l0,l1,l2,l3};
        }
        __syncthreads();

        half8 ah[2], al[2];
        #pragma unroll
        for (int mi = 0; mi < 2; ++mi) {
            int row = (w << 5) + (mi << 4) + lm;
            int off = row * 32 + ((lh ^ (row & 3)) << 3);
            ah[mi] = *(half8*)&Ach[off];
            al[mi] = *(half8*)&Acl[off];
        }
        #pragma unroll
        for (int ni = 0; ni < 8; ++ni) {
            int d = (ni << 4) + lm;
            int off = d * 128 + ((((kc << 2) + lh) ^ (d & 15)) << 3);
            half8 wh = *(half8*)&Wh[off];
            half8 wl = *(half8*)&Wl[off];
            #pragma unroll
            for (int mi = 0; mi < 2; ++mi) {
                acc[mi][ni] = mfma16(ah[mi], wh, acc[mi][ni]);
                acc[mi][ni] = mfma16(al[mi], wh, acc[mi][ni]);
                acc[mi][ni] = mfma16(ah[mi], wl, acc[mi][ni]);
            }
        }
    }

    const float* bias = isU ? Ub : Vb;
    float* dst = isU ? ux : vx;
    #pragma unroll
    for (int ni = 0; ni < 8; ++ni) {
        int d = (ni << 4) + lm;
        float bv = bias[d];
        #pragma unroll
        for (int mi = 0; mi < 2; ++mi) {
            int rbase = r0 + (w << 5) + (mi << 4) + (lh << 2);
            #pragma unroll
            for (int q = 0; q < 4; ++q)
                dst[(size_t)(rbase + q) * C_ + d] = acc[mi][ni][q] + bv;
        }
    }
}

// ---------------- Kernel 3: out_pre = 0.25*sum(vx[nbr]) + ux ; BN partial sums -
__global__ __launch_bounds__(256) void k_agg(const float* __restrict__ vx,
        float* __restrict__ ux, const int* __restrict__ nbr,
        float* __restrict__ stats) {
    __shared__ float red[256 * 8];
    const int tid = threadIdx.x;
    const int r0  = blockIdx.x << 6;
    const int cq  = tid & 31;
    const int rl  = tid >> 5;
    float s0=0,s1=0,s2=0,s3=0, q0=0,q1=0,q2=0,q3=0;
    const float4* vr = (const float4*)vx;
    for (int p = 0; p < 8; ++p) {
        int r = r0 + (p << 3) + rl;
        int4 nb = *(const int4*)(nbr + ((size_t)r << 2));
        int base = (r >> 9) << 9;
        float4 a  = *(const float4*)(ux + (size_t)r*C_ + (cq << 2));
        float4 v0 = vr[(size_t)(base + nb.x)*32 + cq];
        float4 v1 = vr[(size_t)(base + nb.y)*32 + cq];
        float4 v2 = vr[(size_t)(base + nb.z)*32 + cq];
        float4 v3 = vr[(size_t)(base + nb.w)*32 + cq];
        a.x += 0.25f * (v0.x + v1.x + v2.x + v3.x);
        a.y += 0.25f * (v0.y + v1.y + v2.y + v3.y);
        a.z += 0.25f * (v0.z + v1.z + v2.z + v3.z);
        a.w += 0.25f * (v0.w + v1.w + v2.w + v3.w);
        *(float4*)(ux + (size_t)r*C_ + (cq << 2)) = a;
        s0 += a.x; s1 += a.y; s2 += a.z; s3 += a.w;
        q0 += a.x*a.x; q1 += a.y*a.y; q2 += a.z*a.z; q3 += a.w*a.w;
    }
    red[tid*8+0]=s0; red[tid*8+1]=s1; red[tid*8+2]=s2; red[tid*8+3]=s3;
    red[tid*8+4]=q0; red[tid*8+5]=q1; red[tid*8+6]=q2; red[tid*8+7]=q3;
    __syncthreads();
    if (tid < 32) {
        for (int g = 1; g < 8; ++g) {
            int o = (tid + 32*g)*8;
            s0 += red[o+0]; s1 += red[o+1]; s2 += red[o+2]; s3 += red[o+3];
            q0 += red[o+4]; q1 += red[o+5]; q2 += red[o+6]; q3 += red[o+7];
        }
        int c0 = tid*4;
        atomicAdd(&stats[c0+0], s0); atomicAdd(&stats[c0+1], s1);
        atomicAdd(&stats[c0+2], s2); atomicAdd(&stats[c0+3], s3);
        atomicAdd(&stats[128+c0+0], q0); atomicAdd(&stats[128+c0+1], q1);
        atomicAdd(&stats[128+c0+2], q2); atomicAdd(&stats[128+c0+3], q3);
    }
}

// ---------------- Kernel 4: BN normalize + residual + ReLU + transpose --------
__global__ __launch_bounds__(256) void k_fin(const float* __restrict__ x,
        const float* __restrict__ pre, const float* __restrict__ stats,
        const float* __restrict__ gamma, const float* __restrict__ beta,
        float* __restrict__ out) {
    const int id = blockIdx.x * 256 + threadIdx.x;   // float4 id
    const int r  = id >> 5;
    const int c0 = (id & 31) << 2;
    const float inv = 1.0f / (float)R_;
    float4 s  = *(const float4*)(stats + c0);
    float4 sq = *(const float4*)(stats + 128 + c0);
    float4 g  = *(const float4*)(gamma + c0);
    float4 bt = *(const float4*)(beta + c0);
    float m0 = s.x*inv, m1 = s.y*inv, m2 = s.z*inv, m3 = s.w*inv;
    float sc0 = g.x * rsqrtf(sq.x*inv - m0*m0 + BN_EPS);
    float sc1 = g.y * rsqrtf(sq.y*inv - m1*m1 + BN_EPS);
    float sc2 = g.z * rsqrtf(sq.z*inv - m2*m2 + BN_EPS);
    float sc3 = g.w * rsqrtf(sq.w*inv - m3*m3 + BN_EPS);
    float sh0 = bt.x - m0*sc0, sh1 = bt.y - m1*sc1;
    float sh2 = bt.z - m2*sc2, sh3 = bt.w - m3*sc3;
    int n = r >> 9, t = r & 511;
    int off = xbase_n(n) + t*(J_*C_) + c0;
    float4 xv = *(const float4*)(x + off);
    float4 p  = *(const float4*)(pre + (size_t)r*C_ + c0);
    float4 y;
    y.x = xv.x + p.x*sc0 + sh0; y.y = xv.y + p.y*sc1 + sh1;
    y.z = xv.z + p.z*sc2 + sh2; y.w = xv.w + p.w*sc3 + sh3;
    y.x = y.x > 0.f ? y.x : 0.f; y.y = y.y > 0.f ? y.y : 0.f;
    y.z = y.z > 0.f ? y.z : 0.f; y.w = y.w > 0.f ? y.w : 0.f;
    *(float4*)(out + off) = y;
}

extern "C" void kernel_launch(void* const* d_in, const int* in_sizes, int n_in,
                              void* d_out, int out_size, void* d_ws, size_t ws_size,
                              hipStream_t stream) {
    const float* x     = (const float*)d_in[0];
    const float* Uw    = (const float*)d_in[1];
    const float* Ub    = (const float*)d_in[2];
    const float* Vw    = (const float*)d_in[3];
    const float* Vb    = (const float*)d_in[4];
    const float* gamma = (const float*)d_in[5];
    const float* beta  = (const float*)d_in[6];
    float* out = (float*)d_out;

    // workspace layout: ux/out_pre (R*C f32) | nbr (R*4 i32) | stats (256 f32)
    float* ux    = (float*)d_ws;
    int*   nbr   = (int*)(ux + (size_t)R_ * C_);
    float* stats = (float*)(nbr + (size_t)R_ * 4);
    float* vx    = out;   // d_out doubles as vx scratch; overwritten by k_fin

    hipMemsetAsync(stats, 0, 256 * sizeof(float), stream);
    k_sim_topk<<<N_ * 4, 512, 0, stream>>>(x, nbr);
    k_vxux<<<(R_ / 256) * 2, 512, 0, stream>>>(x, Vw, Vb, Uw, Ub, vx, ux);
    k_agg<<<R_ / 64, 256, 0, stream>>>(vx, ux, nbr, stats);
    k_fin<<<(R_ * 32) / 256, 256, 0, stream>>>(x, ux, stats, gamma, beta, out);
}

// Round 5
// 386.778 us; speedup vs baseline: 79.3301x; 1.0149x over previous
//
#include <hip/hip_runtime.h>
#include <math.h>

#define T_ 512
#define J_ 24
#define B_ 8
#define C_ 128
#define N_ (B_*J_)        // 192
#define R_ (N_*T_)        // 98304
#define JC_ (J_*C_)       // 3072
#define BN_EPS 1e-5f

typedef _Float16 half_t;
typedef half_t half8 __attribute__((ext_vector_type(8)));
typedef half_t half4_t __attribute__((ext_vector_type(4)));
typedef float f32x4 __attribute__((ext_vector_type(4)));

__device__ __forceinline__ f32x4 mfma16(half8 a, half8 b, f32x4 c) {
    return __builtin_amdgcn_mfma_f32_16x16x32_f16(a, b, c, 0, 0, 0);
}

// x layout: (B, T, J, C). Row r = n*T + t with n = b*J + j.
__device__ __forceinline__ int xbase_n(int n) {
    int b = n / J_;
    int j = n - b * J_;
    return (b * T_ * J_ + j) * C_;     // add t*(J_*C_) + c
}

__device__ __forceinline__ void split2(float x, half_t& h, half_t& l) {
    half_t hh = (half_t)x;
    h = hh;
    l = (half_t)(x - (float)hh);
}

// chunk swizzle: row stride is 64B (16 banks), so only r&1 reaches bank bits.
// phi(r) spreads the 4 chunk slots so each consecutive-8-lane phase covers
// all 8 bank-groups (conflict-free b128 store AND read).
__device__ __forceinline__ int phi4(int r) { return (r & 3) ^ ((r >> 2) & 3); }

// keep v[0] >= v[1] >= v[2] >= v[3]
__device__ __forceinline__ void ins4(float (&v)[4], int (&ix)[4], float nv, int ni) {
    if (nv > v[3]) {
        if (nv > v[1]) {
            if (nv > v[0]) {
                v[3]=v[2]; ix[3]=ix[2]; v[2]=v[1]; ix[2]=ix[1];
                v[1]=v[0]; ix[1]=ix[0]; v[0]=nv; ix[0]=ni;
            } else {
                v[3]=v[2]; ix[3]=ix[2]; v[2]=v[1]; ix[2]=ix[1];
                v[1]=nv; ix[1]=ni;
            }
        } else {
            if (nv > v[2]) { v[3]=v[2]; ix[3]=ix[2]; v[2]=nv; ix[2]=ni; }
            else           { v[3]=nv; ix[3]=ni; }
        }
    }
}

// ---------------- Kernel 0: one-time fp16 h/l split of x (and U/V weights) --
// xh/xl layout: [n][kc(4)][s(512)][32]  (k-chunked so GEMM staging is a
// contiguous copy). W split kept plain row-major [mat][d][128].
__global__ __launch_bounds__(256) void k_split(const float* __restrict__ x,
        const float* __restrict__ Vw, const float* __restrict__ Uw,
        half_t* __restrict__ xh, half_t* __restrict__ xl,
        half_t* __restrict__ Whg, half_t* __restrict__ Wlg) {
    const int bid = blockIdx.x, tid = threadIdx.x;
    if (bid < 3072) {
        #pragma unroll
        for (int p = 0; p < 4; ++p) {
            int f  = (bid * 4 + p) * 256 + tid;   // float4 id over [r][c4]
            int r  = f >> 5, c4 = f & 31;
            int n  = r >> 9, t = r & 511;
            float4 v = *(const float4*)(x + xbase_n(n) + t * JC_ + (c4 << 2));
            size_t off = ((size_t)((n << 2) + (c4 >> 3)) * 512 + t) * 32 + ((c4 & 7) << 2);
            half_t h0,l0,h1,l1,h2,l2,h3,l3;
            split2(v.x,h0,l0); split2(v.y,h1,l1); split2(v.z,h2,l2); split2(v.w,h3,l3);
            *(half4_t*)&xh[off] = (half4_t){h0,h1,h2,h3};
            *(half4_t*)&xl[off] = (half4_t){l0,l1,l2,l3};
        }
    } else {
        int f  = (bid - 3072) * 256 + tid;        // 0..8191
        int m  = f >> 12;                          // 0=V, 1=U
        int fl = f & 4095;
        int row = fl >> 5, c4 = fl & 31;
        const float* W = m ? Uw : Vw;
        float4 v = *(const float4*)(W + row * C_ + (c4 << 2));
        int off = (m * 128 + row) * 128 + (c4 << 2);
        half_t h0,l0,h1,l1,h2,l2,h3,l3;
        split2(v.x,h0,l0); split2(v.y,h1,l1); split2(v.z,h2,l2); split2(v.w,h3,l3);
        *(half4_t*)&Whg[off] = (half4_t){h0,h1,h2,h3};
        *(half4_t*)&Wlg[off] = (half4_t){l0,l1,l2,l3};
    }
}

// ---------------- Kernel 1: sim top-4 via fp16-split MFMA ---------------------
// Block: 512 thr = 8 waves (wr t-half, wc s-quarter); tile 128t x 512s.
// LDS: double-buffered B slab [512 s][32 k] h+l = 2 x 64KB. A-fragments are
// read FROM the B slab (A rows subset of B rows). Staging = contiguous copy
// from prepass xh/xl, global->reg issued before MFMA, committed after.
__global__ __launch_bounds__(512) void k_sim_topk(const half_t* __restrict__ xh,
        const half_t* __restrict__ xl, int* __restrict__ nbr) {
    __shared__ __align__(16) half_t LB[65536];   // 128 KB: [d][{h:16384,l:16384}]
    float* dump = (float*)LB;                    // [64][512] f32 overlay (post)

    const int bx = (int)blockIdx.x;
    const int wg = (bx & 7) * 96 + (bx >> 3);    // XCD-contiguous
    const int n  = wg >> 2;
    const int t0 = (wg & 3) << 7;
    const int tid = threadIdx.x;
    const int lane = tid & 63;
    const int w    = tid >> 6;
    const int wr   = w >> 2;
    const int wc   = w & 3;
    const int lm   = lane & 15;
    const int lh   = lane >> 4;

    const size_t nb4 = (size_t)(n << 2);
    half8 ph[4], pl[4];

    // issue: contiguous 64B h + 64B l per thread (row = tid)
    auto issue = [&](int kc) {
        const half_t* sh = xh + ((nb4 + kc) * 512 + tid) * 32;
        const half_t* sl = xl + ((nb4 + kc) * 512 + tid) * 32;
        #pragma unroll
        for (int j = 0; j < 4; ++j) { ph[j] = *(const half8*)(sh + j*8); pl[j] = *(const half8*)(sl + j*8); }
    };
    auto commit = [&](int d) {
        half_t* Bh = LB + d * 32768;
        half_t* Bl = Bh + 16384;
        const int rsw = phi4(tid);
        #pragma unroll
        for (int j = 0; j < 4; ++j) {
            int o = tid * 32 + ((j ^ rsw) << 3);
            *(half8*)&Bh[o] = ph[j];
            *(half8*)&Bl[o] = pl[j];
        }
    };

    f32x4 acc[4][8];
    #pragma unroll
    for (int mi = 0; mi < 4; ++mi)
        #pragma unroll
        for (int ni = 0; ni < 8; ++ni) acc[mi][ni] = (f32x4){0.f,0.f,0.f,0.f};

    issue(0); commit(0);
    __syncthreads();

    #pragma unroll 1
    for (int kc = 0; kc < 4; ++kc) {
        if (kc < 3) issue(kc + 1);
        const half_t* Bh = LB + (kc & 1) * 32768;
        const half_t* Bl = Bh + 16384;

        half8 a_h[4], a_l[4];
        #pragma unroll
        for (int mi = 0; mi < 4; ++mi) {
            int rA = t0 + (wr << 6) + (mi << 4) + lm;
            int o  = rA * 32 + ((lh ^ phi4(rA)) << 3);
            a_h[mi] = *(const half8*)&Bh[o];
            a_l[mi] = *(const half8*)&Bl[o];
        }
        #pragma unroll
        for (int ni = 0; ni < 8; ++ni) {
            int rB = (wc << 7) + (ni << 4) + lm;
            int o  = rB * 32 + ((lh ^ phi4(rB)) << 3);
            half8 bh = *(const half8*)&Bh[o];
            half8 bl = *(const half8*)&Bl[o];
            #pragma unroll
            for (int mi = 0; mi < 4; ++mi) {
                acc[mi][ni] = mfma16(a_h[mi], bh, acc[mi][ni]);
                acc[mi][ni] = mfma16(a_l[mi], bh, acc[mi][ni]);
                acc[mi][ni] = mfma16(a_h[mi], bl, acc[mi][ni]);
            }
        }
        if (kc < 3) commit((kc + 1) & 1);
        __syncthreads();
    }

    // ---- top-4: dump 64 rows at a time (f32, col-swizzled), scan, shfl-merge
    #pragma unroll 1
    for (int dr = 0; dr < 2; ++dr) {
        if (wr == dr) {
            #pragma unroll
            for (int mi = 0; mi < 4; ++mi)
                #pragma unroll
                for (int ni = 0; ni < 8; ++ni) {
                    int col = (wc << 7) + (ni << 4) + lm;
                    #pragma unroll
                    for (int q = 0; q < 4; ++q) {
                        int rl = (mi << 4) + (lh << 2) + q;          // 0..63
                        dump[rl * 512 + (col ^ ((rl & 15) << 2))] = acc[mi][ni][q];
                    }
                }
        }
        __syncthreads();
        {
            int rl  = tid >> 3;          // 0..63, 8 threads per row
            int sub = tid & 7;
            int sw  = (rl & 15) << 2;
            float mv[4]; int mi4[4];
            mv[0]=mv[1]=mv[2]=mv[3] = -INFINITY;
            mi4[0]=mi4[1]=mi4[2]=mi4[3] = 0;
            #pragma unroll 4
            for (int j = 0; j < 64; ++j) {
                int c = sub + (j << 3);
                ins4(mv, mi4, dump[rl * 512 + (c ^ sw)], c);
            }
            #pragma unroll
            for (int st = 1; st <= 4; st <<= 1) {
                float rv[4]; int ri[4];
                #pragma unroll
                for (int q = 0; q < 4; ++q) {
                    rv[q] = __shfl_xor(mv[q], st);
                    ri[q] = __shfl_xor(mi4[q], st);
                }
                #pragma unroll
                for (int q = 0; q < 4; ++q) ins4(mv, mi4, rv[q], ri[q]);
            }
            if (sub == 0) {
                int r = n * T_ + t0 + (dr << 6) + rl;
                *(int4*)(nbr + (size_t)r * 4) = make_int4(mi4[0], mi4[1], mi4[2], mi4[3]);
            }
        }
        __syncthreads();
    }
}

// ---------------- Kernel 2: vx = xr Vw^T + Vb ; ux = xr Uw^T + Ub (MFMA) -----
// Block: 512 thr = 8 waves; tile 256 rows x 128 d, one of {V,U} per block.
// W resident (swizzled, 64KB) + A chunk double-buffered (2 x 32KB).
__global__ __launch_bounds__(512) void k_vxux(const half_t* __restrict__ xh,
        const half_t* __restrict__ xl,
        const half_t* __restrict__ Whg, const half_t* __restrict__ Wlg,
        const float* __restrict__ Vb, const float* __restrict__ Ub,
        float* __restrict__ vx, float* __restrict__ ux) {
    __shared__ __align__(16) half_t Wbuf[32768];   // Wh 16384 | Wl 16384
    __shared__ __align__(16) half_t Abuf[32768];   // [d][{Ah 8192, Al 8192}]

    const int bx  = (int)blockIdx.x;
    const int wg  = (bx & 7) * 96 + (bx >> 3);
    const int isU = wg & 1;
    const int r0  = (wg >> 1) << 8;
    const int tid = threadIdx.x;
    const int n   = r0 >> 9;
    const int tb  = r0 & 511;
    const int lane = tid & 63;
    const int w    = tid >> 6;
    const int lm   = lane & 15;
    const int lh   = lane >> 4;

    // stage W (resident): [d][16 chunks], chunk' = j ^ (d&15)
    #pragma unroll
    for (int p = 0; p < 4; ++p) {
        int f = tid + (p << 9);            // 0..2047
        int d = f >> 4, j = f & 15;
        int so = (isU * 128 + d) * 128 + (j << 3);
        int dd = d * 128 + ((j ^ (d & 15)) << 3);
        *(half8*)&Wbuf[dd]         = *(const half8*)&Whg[so];
        *(half8*)&Wbuf[16384 + dd] = *(const half8*)&Wlg[so];
    }

    const size_t nb4 = (size_t)(n << 2);
    half8 pA[4];                           // 2 rows-chunks x {h,l}
    auto issueA = [&](int kc) {
        #pragma unroll
        for (int p = 0; p < 2; ++p) {
            int f = tid + (p << 9);        // 0..1023: r = f>>2, j = f&3
            const half_t* s = xh + ((nb4 + kc) * 512 + tb + (f >> 2)) * 32 + ((f & 3) << 3);
            const half_t* t = xl + ((nb4 + kc) * 512 + tb + (f >> 2)) * 32 + ((f & 3) << 3);
            pA[p]     = *(const half8*)s;
            pA[2 + p] = *(const half8*)t;
        }
    };
    auto commitA = [&](int d) {
        half_t* Ah = Abuf + d * 16384;
        half_t* Al = Ah + 8192;
        #pragma unroll
        for (int p = 0; p < 2; ++p) {
            int f = tid + (p << 9);
            int r = f >> 2, j = f & 3;
            int o = r * 32 + ((j ^ phi4(r)) << 3);
            *(half8*)&Ah[o] = pA[p];
            *(half8*)&Al[o] = pA[2 + p];
        }
    };

    f32x4 acc[2][8];
    #pragma unroll
    for (int mi = 0; mi < 2; ++mi)
        #pragma unroll
        for (int ni = 0; ni < 8; ++ni) acc[mi][ni] = (f32x4){0.f,0.f,0.f,0.f};

    issueA(0); commitA(0);
    __syncthreads();

    #pragma unroll 1
    for (int kc = 0; kc < 4; ++kc) {
        if (kc < 3) issueA(kc + 1);
        const half_t* Ah = Abuf + (kc & 1) * 16384;
        const half_t* Al = Ah + 8192;

        half8 ah[2], al[2];
        #pragma unroll
        for (int mi = 0; mi < 2; ++mi) {
            int row = (w << 5) + (mi << 4) + lm;
            int o   = row * 32 + ((lh ^ phi4(row)) << 3);
            ah[mi] = *(const half8*)&Ah[o];
            al[mi] = *(const half8*)&Al[o];
        }
        #pragma unroll
        for (int ni = 0; ni < 8; ++ni) {
            int d = (ni << 4) + lm;
            int o = d * 128 + ((((kc << 2) + lh) ^ (d & 15)) << 3);
            half8 wh = *(const half8*)&Wbuf[o];
            half8 wl = *(const half8*)&Wbuf[16384 + o];
            #pragma unroll
            for (int mi = 0; mi < 2; ++mi) {
                acc[mi][ni] = mfma16(ah[mi], wh, acc[mi][ni]);
                acc[mi][ni] = mfma16(al[mi], wh, acc[mi][ni]);
                acc[mi][ni] = mfma16(ah[mi], wl, acc[mi][ni]);
            }
        }
        if (kc < 3) commitA((kc + 1) & 1);
        __syncthreads();
    }

    const float* bias = isU ? Ub : Vb;
    float* dst = isU ? ux : vx;
    #pragma unroll
    for (int ni = 0; ni < 8; ++ni) {
        int d = (ni << 4) + lm;
        float bv = bias[d];
        #pragma unroll
        for (int mi = 0; mi < 2; ++mi) {
            int rbase = r0 + (w << 5) + (mi << 4) + (lh << 2);
            #pragma unroll
            for (int q = 0; q < 4; ++q)
                dst[(size_t)(rbase + q) * C_ + d] = acc[mi][ni][q] + bv;
        }
    }
}

// ---------------- Kernel 3: out_pre = 0.25*sum(vx[nbr]) + ux ; BN partial sums -
__global__ __launch_bounds__(256) void k_agg(const float* __restrict__ vx,
        float* __restrict__ ux, const int* __restrict__ nbr,
        float* __restrict__ stats) {
    __shared__ float red[256 * 8];
    const int tid = threadIdx.x;
    const int r0  = blockIdx.x << 6;
    const int cq  = tid & 31;
    const int rl  = tid >> 5;
    float s0=0,s1=0,s2=0,s3=0, q0=0,q1=0,q2=0,q3=0;
    const float4* vr = (const float4*)vx;
    for (int p = 0; p < 8; ++p) {
        int r = r0 + (p << 3) + rl;
        int4 nb = *(const int4*)(nbr + ((size_t)r << 2));
        int base = (r >> 9) << 9;
        float4 a  = *(const float4*)(ux + (size_t)r*C_ + (cq << 2));
        float4 v0 = vr[(size_t)(base + nb.x)*32 + cq];
        float4 v1 = vr[(size_t)(base + nb.y)*32 + cq];
        float4 v2 = vr[(size_t)(base + nb.z)*32 + cq];
        float4 v3 = vr[(size_t)(base + nb.w)*32 + cq];
        a.x += 0.25f * (v0.x + v1.x + v2.x + v3.x);
        a.y += 0.25f * (v0.y + v1.y + v2.y + v3.y);
        a.z += 0.25f * (v0.z + v1.z + v2.z + v3.z);
        a.w += 0.25f * (v0.w + v1.w + v2.w + v3.w);
        *(float4*)(ux + (size_t)r*C_ + (cq << 2)) = a;
        s0 += a.x; s1 += a.y; s2 += a.z; s3 += a.w;
        q0 += a.x*a.x; q1 += a.y*a.y; q2 += a.z*a.z; q3 += a.w*a.w;
    }
    red[tid*8+0]=s0; red[tid*8+1]=s1; red[tid*8+2]=s2; red[tid*8+3]=s3;
    red[tid*8+4]=q0; red[tid*8+5]=q1; red[tid*8+6]=q2; red[tid*8+7]=q3;
    __syncthreads();
    if (tid < 32) {
        for (int g = 1; g < 8; ++g) {
            int o = (tid + 32*g)*8;
            s0 += red[o+0]; s1 += red[o+1]; s2 += red[o+2]; s3 += red[o+3];
            q0 += red[o+4]; q1 += red[o+5]; q2 += red[o+6]; q3 += red[o+7];
        }
        int c0 = tid*4;
        atomicAdd(&stats[c0+0], s0); atomicAdd(&stats[c0+1], s1);
        atomicAdd(&stats[c0+2], s2); atomicAdd(&stats[c0+3], s3);
        atomicAdd(&stats[128+c0+0], q0); atomicAdd(&stats[128+c0+1], q1);
        atomicAdd(&stats[128+c0+2], q2); atomicAdd(&stats[128+c0+3], q3);
    }
}

// ---------------- Kernel 4: BN normalize + residual + ReLU + transpose --------
__global__ __launch_bounds__(256) void k_fin(const float* __restrict__ x,
        const float* __restrict__ pre, const float* __restrict__ stats,
        const float* __restrict__ gamma, const float* __restrict__ beta,
        float* __restrict__ out) {
    const int id = blockIdx.x * 256 + threadIdx.x;   // float4 id
    const int r  = id >> 5;
    const int c0 = (id & 31) << 2;
    const float inv = 1.0f / (float)R_;
    float4 s  = *(const float4*)(stats + c0);
    float4 sq = *(const float4*)(stats + 128 + c0);
    float4 g  = *(const float4*)(gamma + c0);
    float4 bt = *(const float4*)(beta + c0);
    float m0 = s.x*inv, m1 = s.y*inv, m2 = s.z*inv, m3 = s.w*inv;
    float sc0 = g.x * rsqrtf(sq.x*inv - m0*m0 + BN_EPS);
    float sc1 = g.y * rsqrtf(sq.y*inv - m1*m1 + BN_EPS);
    float sc2 = g.z * rsqrtf(sq.z*inv - m2*m2 + BN_EPS);
    float sc3 = g.w * rsqrtf(sq.w*inv - m3*m3 + BN_EPS);
    float sh0 = bt.x - m0*sc0, sh1 = bt.y - m1*sc1;
    float sh2 = bt.z - m2*sc2, sh3 = bt.w - m3*sc3;
    int n = r >> 9, t = r & 511;
    int off = xbase_n(n) + t*(J_*C_) + c0;
    float4 xv = *(const float4*)(x + off);
    float4 p  = *(const float4*)(pre + (size_t)r*C_ + c0);
    float4 y;
    y.x = xv.x + p.x*sc0 + sh0; y.y = xv.y + p.y*sc1 + sh1;
    y.z = xv.z + p.z*sc2 + sh2; y.w = xv.w + p.w*sc3 + sh3;
    y.x = y.x > 0.f ? y.x : 0.f; y.y = y.y > 0.f ? y.y : 0.f;
    y.z = y.z > 0.f ? y.z : 0.f; y.w = y.w > 0.f ? y.w : 0.f;
    *(float4*)(out + off) = y;
}

extern "C" void kernel_launch(void* const* d_in, const int* in_sizes, int n_in,
                              void* d_out, int out_size, void* d_ws, size_t ws_size,
                              hipStream_t stream) {
    const float* x     = (const float*)d_in[0];
    const float* Uw    = (const float*)d_in[1];
    const float* Ub    = (const float*)d_in[2];
    const float* Vw    = (const float*)d_in[3];
    const float* Vb    = (const float*)d_in[4];
    const float* gamma = (const float*)d_in[5];
    const float* beta  = (const float*)d_in[6];
    float* out = (float*)d_out;

    // workspace: ux (R*C f32) | nbr (R*4 i32) | stats (256 f32) |
    //            xh (R*C f16) | xl (R*C f16) | Whg (2*C*C f16) | Wlg (2*C*C f16)
    float*  ux    = (float*)d_ws;
    int*    nbr   = (int*)(ux + (size_t)R_ * C_);
    float*  stats = (float*)(nbr + (size_t)R_ * 4);
    half_t* xh    = (half_t*)(stats + 256);
    half_t* xl    = xh + (size_t)R_ * C_;
    half_t* Whg   = xl + (size_t)R_ * C_;
    half_t* Wlg   = Whg + 2 * C_ * C_;
    float*  vx    = out;   // d_out doubles as vx scratch; overwritten by k_fin

    hipMemsetAsync(stats, 0, 256 * sizeof(float), stream);
    k_split<<<3104, 256, 0, stream>>>(x, Vw, Uw, xh, xl, Whg, Wlg);
    k_sim_topk<<<N_ * 4, 512, 0, stream>>>(xh, xl, nbr);
    k_vxux<<<(R_ / 256) * 2, 512, 0, stream>>>(xh, xl, Whg, Wlg, Vb, Ub, vx, ux);
    k_agg<<<R_ / 64, 256, 0, stream>>>(vx, ux, nbr, stats);
    k_fin<<<(R_ * 32) / 256, 256, 0, stream>>>(x, ux, stats, gamma, beta, out);
}